// Round 4
// baseline (283.705 us; speedup 1.0000x reference)
//
#include <hip/hip_runtime.h>
#include <stdint.h>

typedef unsigned short u16;
typedef __bf16 bf16x8 __attribute__((ext_vector_type(8)));
typedef float f32x4 __attribute__((ext_vector_type(4)));

#define T_SEQ 4096
#define DMODEL 1024

__device__ __forceinline__ float bf2f(u16 x) {
  union { uint32_t u; float f; } v; v.u = ((uint32_t)x) << 16; return v.f;
}
__device__ __forceinline__ u16 f2bf(float f) {
  union { float f; uint32_t u; } v; v.f = f;
  return (u16)((v.u + 0x7FFFu + ((v.u >> 16) & 1u)) >> 16);  // RNE, finite inputs only
}
__device__ __forceinline__ float fexp2(float x) {
#if __has_builtin(__builtin_amdgcn_exp2f)
  return __builtin_amdgcn_exp2f(x);
#else
  return __expf(x * 0.6931471805599453f);
#endif
}
// pack two f32 -> packed bf16x2 (lo in low16)
__device__ __forceinline__ uint32_t pack_bf16(float lo, float hi) {
#if __has_builtin(__builtin_amdgcn_cvt_pk_bf16_f32)
  typedef __bf16 bf16x2_t __attribute__((ext_vector_type(2)));
  union { bf16x2_t v; uint32_t u; } c;
  c.v = __builtin_amdgcn_cvt_pk_bf16_f32(lo, hi);
  return c.u;
#else
  union { float f; uint32_t u; } a, b;
  a.f = lo; b.f = hi;
  return __builtin_amdgcn_perm(b.u + 0x8000u, a.u + 0x8000u, 0x07060302u);
#endif
}
// async global->LDS, 16B/lane. LDS dest = wave-uniform base + lane*16 (guide §5 caveat).
__device__ __forceinline__ void async16(void* lds, const void* g) {
  __builtin_amdgcn_global_load_lds(
      (__attribute__((address_space(1))) void*)const_cast<void*>(g),
      (__attribute__((address_space(3))) void*)lds, 16, 0, 0);
}
__device__ __forceinline__ void storeC(u16* C, size_t i, float v) { C[i] = f2bf(v); }
__device__ __forceinline__ void storeC(float* C, size_t i, float v) { C[i] = v; }

// ---------------- fused prep: fp32->bf16 copy of X + all 5 weight transposes ----
// fp32 [K][N] -> bf16 [N][K]; block-range dispatch, all shapes compile-time.
__device__ __forceinline__ void wtrans_body(const float* __restrict__ in,
                                            u16* __restrict__ out, int K, int N,
                                            int bx, int by, int tid,
                                            float (*tile)[65]) {
  const int n0 = bx * 64, k0 = by * 64;
  const int r = tid >> 2, c = (tid & 3) * 16;
#pragma unroll
  for (int j = 0; j < 4; ++j) {
    float4 v = *(const float4*)&in[(size_t)(k0 + r) * N + n0 + c + j * 4];
    tile[r][c + j * 4 + 0] = v.x; tile[r][c + j * 4 + 1] = v.y;
    tile[r][c + j * 4 + 2] = v.z; tile[r][c + j * 4 + 3] = v.w;
  }
  __syncthreads();
  union { u16 s[16]; uint4 q[2]; } buf;
#pragma unroll
  for (int j = 0; j < 16; ++j) buf.s[j] = f2bf(tile[c + j][r]);
  u16* dst = out + (size_t)(n0 + r) * K + k0 + c;
  *(uint4*)(dst) = buf.q[0];
  *(uint4*)(dst + 8) = buf.q[1];
}

__global__ void __launch_bounds__(256) prep(const float* __restrict__ query,
                                            const float* __restrict__ Wq,
                                            const float* __restrict__ Wk,
                                            const float* __restrict__ Wv,
                                            const float* __restrict__ W1,
                                            const float* __restrict__ W2,
                                            u16* __restrict__ Xb,
                                            u16* __restrict__ WqkvT,
                                            u16* __restrict__ W1T,
                                            u16* __restrict__ W2T) {
  __shared__ float tile[64][65];
  const int b = blockIdx.x, tid = threadIdx.x;
  if (b < 4096) {                       // f2b copy: query -> Xb (4M elems, 4/thread)
    int idx = (b * 256 + tid) * 4;
    float4 v = *(const float4*)(query + idx);
    union { u16 s[4]; uint2 q; } o;
    o.s[0] = f2bf(v.x); o.s[1] = f2bf(v.y); o.s[2] = f2bf(v.z); o.s[3] = f2bf(v.w);
    *(uint2*)(Xb + idx) = o.q;
  } else if (b < 4352) {                // Wq [1024][1024]
    int t = b - 4096;
    wtrans_body(Wq, WqkvT, 1024, 1024, t & 15, t >> 4, tid, tile);
  } else if (b < 4416) {                // Wk [1024][256]
    int t = b - 4352;
    wtrans_body(Wk, WqkvT + (size_t)1024 * 1024, 1024, 256, t & 3, t >> 2, tid, tile);
  } else if (b < 4480) {                // Wv [1024][256]
    int t = b - 4416;
    wtrans_body(Wv, WqkvT + (size_t)1280 * 1024, 1024, 256, t & 3, t >> 2, tid, tile);
  } else if (b < 5504) {                // W1 [1024][4096]
    int t = b - 4480;
    wtrans_body(W1, W1T, 1024, 4096, t & 63, t >> 6, tid, tile);
  } else {                              // W2 [4096][1024]
    int t = b - 5504;
    wtrans_body(W2, W2T, 4096, 1024, t & 15, t >> 4, tid, tile);
  }
}

// ---------------- fused RoPE + V transpose ----------------
// blocks [0,4096): RoPE row t; blocks [4096,4352): V-slice transpose.
__global__ void __launch_bounds__(256) rope_vt(const u16* __restrict__ qkv,
                                               u16* __restrict__ Q,
                                               u16* __restrict__ Ko,
                                               u16* __restrict__ Vt) {
  __shared__ u16 tile[64][65];
  const int b = blockIdx.x, tid = threadIdx.x;
  if (b < 4096) {
    const int t = b;
    const int i = tid & 31;
    const float ang = (float)t * powf(10000.f, -(float)i * (1.f / 32.f));
    float s, c;
    sincosf(ang, &s, &c);
    const u16* row = qkv + (size_t)t * 1536;
    const float QS = 0.125f * 1.4426950408889634f;  // attn scale * log2(e)
    const float cq = c * QS, sq = s * QS;
#pragma unroll
    for (int it = 0; it < 2; ++it) {
      int h = (tid >> 5) + it * 8;
      float x1 = bf2f(row[h * 64 + i]);
      float x2 = bf2f(row[h * 64 + 32 + i]);
      size_t o = ((size_t)h * T_SEQ + t) * 64 + i;
      Q[o] = f2bf(x1 * cq - x2 * sq);
      Q[o + 32] = f2bf(x2 * cq + x1 * sq);
    }
    if (tid < 128) {
      int h = tid >> 5;
      float x1 = bf2f(row[1024 + h * 64 + i]);
      float x2 = bf2f(row[1024 + h * 64 + 32 + i]);
      size_t o = ((size_t)h * T_SEQ + t) * 64 + i;
      Ko[o] = f2bf(x1 * c - x2 * s);
      Ko[o + 32] = f2bf(x2 * c + x1 * s);
    }
  } else {
    const int t = b - 4096;
    const int t0 = (t & 63) * 64, h = t >> 6;
    const int r = tid >> 2, q4 = (tid & 3) * 16;
    const u16* src = qkv + (size_t)(t0 + r) * 1536 + 1280 + h * 64 + q4;
    union { u16 s[16]; uint4 q[2]; } buf;
    buf.q[0] = *(const uint4*)(src);
    buf.q[1] = *(const uint4*)(src + 8);
#pragma unroll
    for (int j = 0; j < 16; ++j) tile[r][q4 + j] = buf.s[j];
    __syncthreads();
#pragma unroll
    for (int j = 0; j < 16; ++j) buf.s[j] = tile[q4 + j][r];
    u16* dst = Vt + ((size_t)h * 64 + r) * T_SEQ + t0 + q4;
    *(uint4*)(dst) = buf.q[0];
    *(uint4*)(dst + 8) = buf.q[1];
  }
}

// ---------------- bf16 GEMM: C[M][N] = A[M][K] @ Bt[N][K]^T ----------------
// R3: double-buffered LDS + prefetch-before-compute + ONE barrier per K-step.
template <int AM, int ACT, typename OutT>
__global__ void __launch_bounds__(256) gemm_bt(const u16* __restrict__ A,
                                               const u16* __restrict__ Bt,
                                               OutT* __restrict__ C,
                                               int M, int N, int K) {
  __shared__ u16 sA[2][AM * 32][64];
  __shared__ u16 sB[2][128][64];
  const int tid = threadIdx.x;
  const int w = tid >> 6, lane = tid & 63;
  const int g = lane >> 4, l15 = lane & 15;
  const int r8 = lane >> 3, c8 = lane & 7;
  const int bm = blockIdx.y * (AM * 32), bn = blockIdx.x * 128;

  f32x4 acc[AM][4];
#pragma unroll
  for (int i = 0; i < AM; ++i)
#pragma unroll
    for (int j = 0; j < 4; ++j) acc[i][j] = (f32x4){0.f, 0.f, 0.f, 0.f};

  const u16* Ag = A + (size_t)(bm + w * (AM * 8) + r8) * K + (c8 ^ r8) * 8;
  const u16* Bg = Bt + (size_t)(bn + w * 32 + r8) * K + (c8 ^ r8) * 8;
  const int mrow = (w >> 1) * (AM * 16), ncol = (w & 1) * 64;
  const int swz = l15 & 7;

#define GSTAGE(K0, BUF)                                                        \
  {                                                                            \
    _Pragma("unroll") for (int t = 0; t < AM; ++t)                             \
      async16(&sA[BUF][w * (AM * 8) + t * 8][0], Ag + (size_t)(t * 8) * K + (K0)); \
    _Pragma("unroll") for (int t = 0; t < 4; ++t)                              \
      async16(&sB[BUF][w * 32 + t * 8][0], Bg + (size_t)(t * 8) * K + (K0));   \
  }

  GSTAGE(0, 0);
  int cur = 0;
  for (int k0 = 0; k0 < K; k0 += 64) {
    __syncthreads();                       // drains prefetch of cur; protects cur^1 reuse
    if (k0 + 64 < K) GSTAGE(k0 + 64, cur ^ 1);
#pragma unroll
    for (int kk = 0; kk < 2; ++kk) {
      const int cb = ((kk * 4 + g) ^ swz) * 8;
      bf16x8 a[AM], b[4];
#pragma unroll
      for (int i = 0; i < AM; ++i) a[i] = *(const bf16x8*)&sA[cur][mrow + i * 16 + l15][cb];
#pragma unroll
      for (int i = 0; i < 4; ++i) b[i] = *(const bf16x8*)&sB[cur][ncol + i * 16 + l15][cb];
#pragma unroll
      for (int mi = 0; mi < AM; ++mi)
#pragma unroll
        for (int ni = 0; ni < 4; ++ni)
          acc[mi][ni] = __builtin_amdgcn_mfma_f32_16x16x32_bf16(a[mi], b[ni], acc[mi][ni], 0, 0, 0);
    }
    cur ^= 1;
  }
#undef GSTAGE
#pragma unroll
  for (int mi = 0; mi < AM; ++mi)
#pragma unroll
    for (int ni = 0; ni < 4; ++ni)
#pragma unroll
      for (int r = 0; r < 4; ++r) {
        int row = bm + mrow + mi * 16 + g * 4 + r;
        int col = bn + ncol + ni * 16 + l15;
        float v = acc[mi][ni][r];
        if (ACT == 1) v = v / (1.f + __expf(-v));  // SiLU
        storeC(C, (size_t)row * N + col, v);
      }
}

// ---------------- W2 GEMM, AM=4 + split-K x2 ----------------
// out[4096][1024] (fp32) = H[4096][4096] @ W2T[1024][4096]^T.
// z=0 covers k<2048 -> fp32 partial straight into out; z=1 covers k>=2048 ->
// bf16 partial into P1 (aliases dead W1T). w2_combine: out += bf16(P1).
// R3: same double-buffer + prefetch-before-compute transformation as gemm_bt.
__global__ void __launch_bounds__(256, 2) gemm_w2(const u16* __restrict__ A,
                                                  const u16* __restrict__ Bt,
                                                  float* __restrict__ C0,
                                                  u16* __restrict__ C1) {
  __shared__ u16 sA[2][128][64];
  __shared__ u16 sB[2][128][64];
  const int K = 4096, N = 1024;
  const int z = blockIdx.z, koff = z * 2048;
  const int tid = threadIdx.x;
  const int w = tid >> 6, lane = tid & 63;
  const int g = lane >> 4, l15 = lane & 15;
  const int r8 = lane >> 3, c8 = lane & 7;
  const int bm = blockIdx.y * 128, bn = blockIdx.x * 128;

  f32x4 acc[4][4];
#pragma unroll
  for (int i = 0; i < 4; ++i)
#pragma unroll
    for (int j = 0; j < 4; ++j) acc[i][j] = (f32x4){0.f, 0.f, 0.f, 0.f};

  const u16* Ag = A + (size_t)(bm + w * 32 + r8) * K + koff + (c8 ^ r8) * 8;
  const u16* Bg = Bt + (size_t)(bn + w * 32 + r8) * K + koff + (c8 ^ r8) * 8;
  const int mrow = (w >> 1) * 64, ncol = (w & 1) * 64;
  const int swz = l15 & 7;

#define GSTAGE(K0, BUF)                                                   \
  {                                                                       \
    _Pragma("unroll") for (int t = 0; t < 4; ++t) {                       \
      async16(&sA[BUF][w * 32 + t * 8][0], Ag + (size_t)(t * 8) * K + (K0)); \
      async16(&sB[BUF][w * 32 + t * 8][0], Bg + (size_t)(t * 8) * K + (K0)); \
    }                                                                     \
  }

  GSTAGE(0, 0);
  int cur = 0;
  for (int k0 = 0; k0 < 2048; k0 += 64) {
    __syncthreads();
    if (k0 + 64 < 2048) GSTAGE(k0 + 64, cur ^ 1);
#pragma unroll
    for (int kk = 0; kk < 2; ++kk) {
      const int cb = ((kk * 4 + g) ^ swz) * 8;
      bf16x8 a[4], b[4];
#pragma unroll
      for (int i = 0; i < 4; ++i) {
        a[i] = *(const bf16x8*)&sA[cur][mrow + i * 16 + l15][cb];
        b[i] = *(const bf16x8*)&sB[cur][ncol + i * 16 + l15][cb];
      }
#pragma unroll
      for (int mi = 0; mi < 4; ++mi)
#pragma unroll
        for (int ni = 0; ni < 4; ++ni)
          acc[mi][ni] = __builtin_amdgcn_mfma_f32_16x16x32_bf16(a[mi], b[ni], acc[mi][ni], 0, 0, 0);
    }
    cur ^= 1;
  }
#undef GSTAGE
#pragma unroll
  for (int mi = 0; mi < 4; ++mi)
#pragma unroll
    for (int ni = 0; ni < 4; ++ni)
#pragma unroll
      for (int r = 0; r < 4; ++r) {
        size_t idx = (size_t)(bm + mrow + mi * 16 + g * 4 + r) * N + bn + ncol + ni * 16 + l15;
        if (z == 0) C0[idx] = acc[mi][ni][r];
        else        C1[idx] = f2bf(acc[mi][ni][r]);
      }
}

__global__ void __launch_bounds__(256) w2_combine(float* __restrict__ out,
                                                  const u16* __restrict__ P1) {
  int idx = (blockIdx.x * 256 + threadIdx.x) * 4;
  float4 v = *(const float4*)(out + idx);
  union { uint2 q; u16 s[4]; } p;
  p.q = *(const uint2*)(P1 + idx);
  v.x += bf2f(p.s[0]); v.y += bf2f(p.s[1]);
  v.z += bf2f(p.s[2]); v.w += bf2f(p.s[3]);
  *(float4*)(out + idx) = v;
}

// ---------------- Flash attention (causal, GQA 16q/4kv, D=64) ----------------
// 128-row q-tile pairs (t0=pr, t1=31-pr) x kv-parity split: 512 equal blocks.
// R4: 1-tile software pipeline (T15). Per iter: QK(i) [matrix] -> PV(i-1)
// [matrix, independent, reads sP from last iter] -> exp/pack(i) [VALU, waits
// only on QK(i), overlaps PV's MFMAs] -> sP write. V gets a 3rd buffer so
// STAGE(i+1) never overwrites V(i-1) mid-PV. sP stays full-size, halves stay
// parallel (R1 lesson). LDS 74.8KB -> still 2 blocks/CU.
__global__ void __launch_bounds__(256, 2) attn(const u16* __restrict__ Q,
                                               const u16* __restrict__ K,
                                               const u16* __restrict__ Vt,
                                               u16* __restrict__ O0,
                                               u16* __restrict__ O1,
                                               float* __restrict__ L0,
                                               float* __restrict__ L1) {
  __shared__ u16 sK[2][64][64];
  __shared__ u16 sV[3][64][64];     // sV[vb][d][kv], triple-buffered
  __shared__ u16 sP[4][64][68];     // [wave][half*32+mi*16+q16][kv] pad+4
  const int pr = blockIdx.x >> 1;
  const int split = blockIdx.x & 1;
  const int h = blockIdx.y;
  const int kvh = h >> 2;
  const int tid = threadIdx.x;
  const int w = tid >> 6, lane = tid & 63;
  const int g = lane >> 4, l15 = lane & 15;
  const int r8 = lane >> 3, c8 = lane & 7;
  const int swz = l15 & 7;
  const int t0 = pr, t1 = 31 - pr;
  const int off = split * 64;

  u16* Op = split ? O1 : O0;
  float* Lp = split ? L1 : L0;

  bf16x8 qf[2][2][2];
  {
    const u16* Qh = Q + (size_t)h * T_SEQ * 64;
#pragma unroll
    for (int half = 0; half < 2; ++half)
#pragma unroll
      for (int mi = 0; mi < 2; ++mi) {
        const int q = (half ? t1 : t0) * 128 + w * 32 + mi * 16 + l15;
#pragma unroll
        for (int kk = 0; kk < 2; ++kk)
          qf[half][mi][kk] = *(const bf16x8*)(Qh + (size_t)q * 64 + (kk * 4 + g) * 8);
      }
  }

  f32x4 oacc[2][2][4];
  f32x4 lacc[2][2];
#pragma unroll
  for (int half = 0; half < 2; ++half)
#pragma unroll
    for (int mi = 0; mi < 2; ++mi) {
      lacc[half][mi] = (f32x4){0.f, 0.f, 0.f, 0.f};
#pragma unroll
      for (int nd = 0; nd < 4; ++nd) oacc[half][mi][nd] = (f32x4){0.f, 0.f, 0.f, 0.f};
    }

  bf16x8 ONES;
  {
    union { u16 s[8]; bf16x8 v; } o;
#pragma unroll
    for (int i = 0; i < 8; ++i) o.s[i] = 0x3F80;  // bf16 1.0
    ONES = o.v;
  }

  const u16* Kg = K + ((size_t)kvh * T_SEQ + w * 16 + r8) * 64 + (c8 ^ r8) * 8;
  const u16* Vg = Vt + ((size_t)kvh * 64 + w * 16 + r8) * T_SEQ + (c8 ^ r8) * 8;

  f32x4 s1[2][4], s0[2][4];        // QK scores of current tile (transient)
  uint2 pk1[2][4], pk0[2][4];      // packed P of current tile (written to sP at iter end)

#define STAGE2(J, KB, VB)                                               \
  {                                                                     \
    const int kv0_ = (J) * 64;                                          \
    async16(&sK[KB][w * 16 + 0][0], Kg + (size_t)kv0_ * 64);            \
    async16(&sK[KB][w * 16 + 8][0], Kg + (size_t)(kv0_ + 8) * 64);      \
    async16(&sV[VB][w * 16 + 0][0], Vg + kv0_);                         \
    async16(&sV[VB][w * 16 + 8][0], Vg + (size_t)8 * T_SEQ + kv0_);     \
  }

#define QKMM(B, ACT0)                                                             \
  {                                                                               \
    _Pragma("unroll") for (int mi = 0; mi < 2; ++mi)                              \
    _Pragma("unroll") for (int kt = 0; kt < 4; ++kt) {                            \
      s1[mi][kt] = (f32x4){0.f, 0.f, 0.f, 0.f};                                   \
      if (ACT0) s0[mi][kt] = (f32x4){0.f, 0.f, 0.f, 0.f};                         \
    }                                                                             \
    __builtin_amdgcn_s_setprio(1);                                                \
    _Pragma("unroll") for (int kt = 0; kt < 4; ++kt)                              \
    _Pragma("unroll") for (int kk = 0; kk < 2; ++kk) {                            \
      bf16x8 kf = *(const bf16x8*)&sK[B][kt * 16 + l15][((kk * 4 + g) ^ swz) * 8]; \
      _Pragma("unroll") for (int mi = 0; mi < 2; ++mi) {                          \
        s1[mi][kt] = __builtin_amdgcn_mfma_f32_16x16x32_bf16(kf, qf[1][mi][kk], s1[mi][kt], 0, 0, 0); \
        if (ACT0)                                                                 \
          s0[mi][kt] = __builtin_amdgcn_mfma_f32_16x16x32_bf16(kf, qf[0][mi][kk], s0[mi][kt], 0, 0, 0); \
      }                                                                           \
    }                                                                             \
    __builtin_amdgcn_s_setprio(0);                                                \
  }

// PV + l-acc of the PREVIOUS tile: reads sP (written last iter) + sV[VB].
#define PVL(PACT0, VB)                                                            \
  {                                                                               \
    __builtin_amdgcn_s_setprio(1);                                                \
    _Pragma("unroll") for (int kk = 0; kk < 2; ++kk) {                            \
      bf16x8 pf1[2], pf0[2];                                                      \
      _Pragma("unroll") for (int mi = 0; mi < 2; ++mi) {                          \
        pf1[mi] = *(const bf16x8*)&sP[w][32 + mi * 16 + l15][kk * 32 + g * 8];    \
        if (PACT0) pf0[mi] = *(const bf16x8*)&sP[w][mi * 16 + l15][kk * 32 + g * 8]; \
      }                                                                           \
      _Pragma("unroll") for (int mi = 0; mi < 2; ++mi) {                          \
        lacc[1][mi] = __builtin_amdgcn_mfma_f32_16x16x32_bf16(pf1[mi], ONES, lacc[1][mi], 0, 0, 0); \
        if (PACT0)                                                                \
          lacc[0][mi] = __builtin_amdgcn_mfma_f32_16x16x32_bf16(pf0[mi], ONES, lacc[0][mi], 0, 0, 0); \
      }                                                                           \
      _Pragma("unroll") for (int nd = 0; nd < 4; ++nd) {                          \
        bf16x8 vf = *(const bf16x8*)&sV[VB][nd * 16 + l15][((kk * 4 + g) ^ swz) * 8]; \
        _Pragma("unroll") for (int mi = 0; mi < 2; ++mi) {                        \
          oacc[1][mi][nd] = __builtin_amdgcn_mfma_f32_16x16x32_bf16(pf1[mi], vf, oacc[1][mi][nd], 0, 0, 0); \
          if (PACT0)                                                              \
            oacc[0][mi][nd] = __builtin_amdgcn_mfma_f32_16x16x32_bf16(pf0[mi], vf, oacc[0][mi][nd], 0, 0, 0); \
        }                                                                         \
      }                                                                           \
    }                                                                             \
    __builtin_amdgcn_s_setprio(0);                                                \
  }

// exp + causal-mask + pack of current tile's scores into pk regs.
#define EXPPK(ACT0, M0, M1)                                                       \
  {                                                                               \
    _Pragma("unroll") for (int mi = 0; mi < 2; ++mi) {                            \
      const int thr_ = w * 32 + mi * 16 + l15 - off;                              \
      _Pragma("unroll") for (int kt = 0; kt < 4; ++kt) {                          \
        float p_[4];                                                              \
        _Pragma("unroll") for (int r = 0; r < 4; ++r) {                           \
          float p = fexp2(s1[mi][kt][r]);                                         \
          if (M1 && (kt * 16 + g * 4 + r > thr_)) p = 0.f;                        \
          p_[r] = p;                                                              \
        }                                                                         \
        pk1[mi][kt].x = pack_bf16(p_[0], p_[1]);                                  \
        pk1[mi][kt].y = pack_bf16(p_[2], p_[3]);                                  \
        if (ACT0) {                                                               \
          float q_[4];                                                            \
          _Pragma("unroll") for (int r = 0; r < 4; ++r) {                         \
            float p = fexp2(s0[mi][kt][r]);                                       \
            if (M0 && (kt * 16 + g * 4 + r > thr_)) p = 0.f;                      \
            q_[r] = p;                                                            \
          }                                                                       \
          pk0[mi][kt].x = pack_bf16(q_[0], q_[1]);                                \
          pk0[mi][kt].y = pack_bf16(q_[2], q_[3]);                                \
        }                                                                         \
      }                                                                           \
    }                                                                             \
  }

#define SPW(ACT0)                                                                 \
  {                                                                               \
    _Pragma("unroll") for (int mi = 0; mi < 2; ++mi)                              \
    _Pragma("unroll") for (int kt = 0; kt < 4; ++kt) {                            \
      *(uint2*)&sP[w][32 + mi * 16 + l15][kt * 16 + g * 4] = pk1[mi][kt];         \
      if (ACT0) *(uint2*)&sP[w][mi * 16 + l15][kt * 16 + g * 4] = pk0[mi][kt];    \
    }                                                                             \
  }

  // Tile sequence: i = 0..t1, kv-block jj = split + 2i. Tile i is:
  //   i < t0 : dual, no mask;  i == t0 : dual, mask half0;
  //   t0 < i < t1 : single (half1);  i == t1 : single, masked.
  // Pipeline invariant entering iter i: vp = V(T_{i-1}), vc = V(T_i), vn free;
  // sP holds P(T_{i-1}); sK[b] = K(T_i) (staged last iter).
  // --- prologue: tile 0 ---
  STAGE2(split, 0, 0);
  __syncthreads();
  STAGE2(split + 2, 1, 1);             // tile 1 always exists (t1 >= 16)
  QKMM(0, true);
  if (t0 == 0) { EXPPK(true, true, false); }
  else         { EXPPK(true, false, false); }
  SPW(true);
  int b = 1;
  int vp = 0, vc = 1, vn = 2;
  int i = 1;
  // --- P1: dual, no mask (prev dual) ---
  for (; i < t0; ++i) {
    __syncthreads();
    STAGE2(split + 2 * (i + 1), b ^ 1, vn);
    QKMM(b, true);
    PVL(true, vp);
    EXPPK(true, false, false);
    __builtin_amdgcn_wave_barrier();
    SPW(true);
    b ^= 1; int tmp = vp; vp = vc; vc = vn; vn = tmp;
  }
  // --- P2: i == t0 (if t0 >= 1): dual, mask half0 (prev dual) ---
  if (t0 >= 1) {
    __syncthreads();
    STAGE2(split + 2 * (i + 1), b ^ 1, vn);   // i+1 = t0+1 <= t1
    QKMM(b, true);
    PVL(true, vp);
    EXPPK(true, true, false);
    __builtin_amdgcn_wave_barrier();
    SPW(true);
    b ^= 1; int tmp = vp; vp = vc; vc = vn; vn = tmp;
    ++i;
  }
  if (i < t1) {
    // --- P3a: first single (prev dual) ---
    __syncthreads();
    STAGE2(split + 2 * (i + 1), b ^ 1, vn);
    QKMM(b, false);
    PVL(true, vp);
    EXPPK(false, false, false);
    __builtin_amdgcn_wave_barrier();
    SPW(false);
    b ^= 1; { int tmp = vp; vp = vc; vc = vn; vn = tmp; }
    ++i;
    // --- P3: singles (prev single) ---
    for (; i < t1; ++i) {
      __syncthreads();
      STAGE2(split + 2 * (i + 1), b ^ 1, vn);
      QKMM(b, false);
      PVL(false, vp);
      EXPPK(false, false, false);
      __builtin_amdgcn_wave_barrier();
      SPW(false);
      b ^= 1; int tmp = vp; vp = vc; vc = vn; vn = tmp;
    }
    // --- P4: i == t1: single, masked (prev single) ---
    __syncthreads();
    QKMM(b, false);
    PVL(false, vp);
    EXPPK(false, false, true);
    __builtin_amdgcn_wave_barrier();
    SPW(false);
    // --- drain: PV of last tile (single) ---
    __builtin_amdgcn_wave_barrier();
    PVL(false, vc);
  } else {
    // t1 == t0 + 1 (pr == 15): P4 directly, prev = dual-masked tile
    __syncthreads();
    QKMM(b, false);
    PVL(true, vp);
    EXPPK(false, false, true);
    __builtin_amdgcn_wave_barrier();
    SPW(false);
    __builtin_amdgcn_wave_barrier();
    PVL(false, vc);
  }
#undef STAGE2
#undef QKMM
#undef PVL
#undef EXPPK
#undef SPW

  // epilogue: write UNNORMALIZED partial O (bf16) + partial l (f32)
#pragma unroll
  for (int half = 0; half < 2; ++half) {
    const int tb = (half ? t1 : t0) * 128;
#pragma unroll
    for (int mi = 0; mi < 2; ++mi)
#pragma unroll
      for (int r = 0; r < 4; ++r) {
        const int trow = tb + w * 32 + mi * 16 + g * 4 + r;
#pragma unroll
        for (int nd = 0; nd < 4; ++nd)
          Op[(size_t)trow * DMODEL + h * 64 + nd * 16 + l15] = f2bf(oacc[half][mi][nd][r]);
        if (l15 == 0) Lp[h * T_SEQ + trow] = lacc[half][mi][r];
      }
  }
}

// ---------------- combine partials: AO = (O0+O1)/(l0+l1) ----------------
__global__ void __launch_bounds__(256) attn_combine(const u16* __restrict__ O0,
                                                    const u16* __restrict__ O1,
                                                    const float* __restrict__ L0,
                                                    const float* __restrict__ L1,
                                                    u16* __restrict__ AO) {
  const int t = blockIdx.x, tid = threadIdx.x;
  const int h = tid >> 4, d4 = (tid & 15) * 4;
  const float inv = 1.f / (L0[h * T_SEQ + t] + L1[h * T_SEQ + t]);
  const size_t idx = (size_t)t * DMODEL + h * 64 + d4;
  union { uint2 q; u16 s[4]; } a, b, o;
  a.q = *(const uint2*)(O0 + idx);
  b.q = *(const uint2*)(O1 + idx);
#pragma unroll
  for (int i = 0; i < 4; ++i) o.s[i] = f2bf((bf2f(a.s[i]) + bf2f(b.s[i])) * inv);
  *(uint2*)(AO + idx) = o.q;
}

// ---------------------------------------------------------------------------
extern "C" void kernel_launch(void* const* d_in, const int* in_sizes, int n_in,
                              void* d_out, int out_size, void* d_ws, size_t ws_size,
                              hipStream_t stream) {
  const float* query = (const float*)d_in[0];
  const float* Wq = (const float*)d_in[1];
  const float* Wk = (const float*)d_in[2];
  const float* Wv = (const float*)d_in[3];
  const float* W1 = (const float*)d_in[4];
  const float* W2 = (const float*)d_in[5];
  float* out = (float*)d_out;

  char* ws = (char*)d_ws;
  size_t off = 0;
  auto alloc = [&](size_t bytes) { char* p = ws + off; off += (bytes + 255) & ~(size_t)255; return p; };
  // Region A (32 MB) -- all dead after attention; H aliases it.
  u16* Xb   = (u16*)alloc((size_t)4096 * 1024 * 2);
  u16* QKVb = (u16*)alloc((size_t)4096 * 1536 * 2);
  u16* Qb   = (u16*)alloc((size_t)16 * 4096 * 64 * 2);
  u16* Kb   = (u16*)alloc((size_t)4 * 4096 * 64 * 2);
  u16* Vtb  = (u16*)alloc((size_t)4 * 4096 * 64 * 2);
  u16* H    = (u16*)ws;  // [4096][4096] bf16 = 32 MB, aliases region A
  // Attention partials alias Xb / QKVb (dead by the time attn runs):
  u16*   O0p = Xb;                               // 8 MB
  u16*   O1p = QKVb;                             // 8 MB
  float* L0p = (float*)(QKVb + (size_t)4096 * 1024);  // 256 KB
  float* L1p = L0p + 16 * T_SEQ;                      // 256 KB
  // Region B
  u16* WqkvT = (u16*)alloc((size_t)1536 * 1024 * 2);
  u16* W1T   = (u16*)alloc((size_t)4096 * 1024 * 2);
  u16* W2T   = (u16*)alloc((size_t)1024 * 4096 * 2);
  u16* AO    = (u16*)alloc((size_t)4096 * 1024 * 2);
  u16* P1    = W1T;  // W2 split-K bf16 partial, aliases dead W1T (8 MB)
  (void)ws_size; (void)in_sizes; (void)n_in; (void)out_size;

  prep<<<6528, 256, 0, stream>>>(query, Wq, Wk, Wv, W1, W2, Xb, WqkvT, W1T, W2T);
  gemm_bt<2, 0, u16><<<dim3(12, 64), 256, 0, stream>>>(Xb, WqkvT, QKVb, 4096, 1536, 1024);
  rope_vt<<<4352, 256, 0, stream>>>(QKVb, Qb, Kb, Vtb);
  attn<<<dim3(32, 16), 256, 0, stream>>>(Qb, Kb, Vtb, O0p, O1p, L0p, L1p);
  attn_combine<<<4096, 256, 0, stream>>>(O0p, O1p, L0p, L1p, AO);
  gemm_bt<4, 1, u16><<<dim3(32, 32), 256, 0, stream>>>(AO, W1T, H, 4096, 4096, 1024);
  gemm_w2<<<dim3(8, 32, 2), 256, 0, stream>>>(H, W2T, out, P1);
  w2_combine<<<4096, 256, 0, stream>>>(out, P1);
}

// Round 5
// 278.059 us; speedup vs baseline: 1.0203x; 1.0203x over previous
//
#include <hip/hip_runtime.h>
#include <stdint.h>

typedef unsigned short u16;
typedef __bf16 bf16x8 __attribute__((ext_vector_type(8)));
typedef float f32x4 __attribute__((ext_vector_type(4)));

#define T_SEQ 4096
#define DMODEL 1024

__device__ __forceinline__ float bf2f(u16 x) {
  union { uint32_t u; float f; } v; v.u = ((uint32_t)x) << 16; return v.f;
}
__device__ __forceinline__ u16 f2bf(float f) {
  union { float f; uint32_t u; } v; v.f = f;
  return (u16)((v.u + 0x7FFFu + ((v.u >> 16) & 1u)) >> 16);  // RNE, finite inputs only
}
__device__ __forceinline__ float fexp2(float x) {
#if __has_builtin(__builtin_amdgcn_exp2f)
  return __builtin_amdgcn_exp2f(x);
#else
  return __expf(x * 0.6931471805599453f);
#endif
}
// pack two f32 -> packed bf16x2 (lo in low16)
__device__ __forceinline__ uint32_t pack_bf16(float lo, float hi) {
#if __has_builtin(__builtin_amdgcn_cvt_pk_bf16_f32)
  typedef __bf16 bf16x2_t __attribute__((ext_vector_type(2)));
  union { bf16x2_t v; uint32_t u; } c;
  c.v = __builtin_amdgcn_cvt_pk_bf16_f32(lo, hi);
  return c.u;
#else
  union { float f; uint32_t u; } a, b;
  a.f = lo; b.f = hi;
  return __builtin_amdgcn_perm(b.u + 0x8000u, a.u + 0x8000u, 0x07060302u);
#endif
}
// async global->LDS, 16B/lane. LDS dest = wave-uniform base + lane*16 (guide §5 caveat).
__device__ __forceinline__ void async16(void* lds, const void* g) {
  __builtin_amdgcn_global_load_lds(
      (__attribute__((address_space(1))) void*)const_cast<void*>(g),
      (__attribute__((address_space(3))) void*)lds, 16, 0, 0);
}
__device__ __forceinline__ void storeC(u16* C, size_t i, float v) { C[i] = f2bf(v); }
__device__ __forceinline__ void storeC(float* C, size_t i, float v) { C[i] = v; }

// ---------------- fused prep: fp32->bf16 copy of X + all 5 weight transposes ----
// fp32 [K][N] -> bf16 [N][K]; block-range dispatch, all shapes compile-time.
__device__ __forceinline__ void wtrans_body(const float* __restrict__ in,
                                            u16* __restrict__ out, int K, int N,
                                            int bx, int by, int tid,
                                            float (*tile)[65]) {
  const int n0 = bx * 64, k0 = by * 64;
  const int r = tid >> 2, c = (tid & 3) * 16;
#pragma unroll
  for (int j = 0; j < 4; ++j) {
    float4 v = *(const float4*)&in[(size_t)(k0 + r) * N + n0 + c + j * 4];
    tile[r][c + j * 4 + 0] = v.x; tile[r][c + j * 4 + 1] = v.y;
    tile[r][c + j * 4 + 2] = v.z; tile[r][c + j * 4 + 3] = v.w;
  }
  __syncthreads();
  union { u16 s[16]; uint4 q[2]; } buf;
#pragma unroll
  for (int j = 0; j < 16; ++j) buf.s[j] = f2bf(tile[c + j][r]);
  u16* dst = out + (size_t)(n0 + r) * K + k0 + c;
  *(uint4*)(dst) = buf.q[0];
  *(uint4*)(dst + 8) = buf.q[1];
}

__global__ void __launch_bounds__(256) prep(const float* __restrict__ query,
                                            const float* __restrict__ Wq,
                                            const float* __restrict__ Wk,
                                            const float* __restrict__ Wv,
                                            const float* __restrict__ W1,
                                            const float* __restrict__ W2,
                                            u16* __restrict__ Xb,
                                            u16* __restrict__ WqkvT,
                                            u16* __restrict__ W1T,
                                            u16* __restrict__ W2T) {
  __shared__ float tile[64][65];
  const int b = blockIdx.x, tid = threadIdx.x;
  if (b < 4096) {                       // f2b copy: query -> Xb (4M elems, 4/thread)
    int idx = (b * 256 + tid) * 4;
    float4 v = *(const float4*)(query + idx);
    union { u16 s[4]; uint2 q; } o;
    o.s[0] = f2bf(v.x); o.s[1] = f2bf(v.y); o.s[2] = f2bf(v.z); o.s[3] = f2bf(v.w);
    *(uint2*)(Xb + idx) = o.q;
  } else if (b < 4352) {                // Wq [1024][1024]
    int t = b - 4096;
    wtrans_body(Wq, WqkvT, 1024, 1024, t & 15, t >> 4, tid, tile);
  } else if (b < 4416) {                // Wk [1024][256]
    int t = b - 4352;
    wtrans_body(Wk, WqkvT + (size_t)1024 * 1024, 1024, 256, t & 3, t >> 2, tid, tile);
  } else if (b < 4480) {                // Wv [1024][256]
    int t = b - 4416;
    wtrans_body(Wv, WqkvT + (size_t)1280 * 1024, 1024, 256, t & 3, t >> 2, tid, tile);
  } else if (b < 5504) {                // W1 [1024][4096]
    int t = b - 4480;
    wtrans_body(W1, W1T, 1024, 4096, t & 63, t >> 6, tid, tile);
  } else {                              // W2 [4096][1024]
    int t = b - 5504;
    wtrans_body(W2, W2T, 4096, 1024, t & 15, t >> 4, tid, tile);
  }
}

// ---------------- fused RoPE + V transpose ----------------
// blocks [0,4096): RoPE row t; blocks [4096,4352): V-slice transpose.
__global__ void __launch_bounds__(256) rope_vt(const u16* __restrict__ qkv,
                                               u16* __restrict__ Q,
                                               u16* __restrict__ Ko,
                                               u16* __restrict__ Vt) {
  __shared__ u16 tile[64][65];
  const int b = blockIdx.x, tid = threadIdx.x;
  if (b < 4096) {
    const int t = b;
    const int i = tid & 31;
    const float ang = (float)t * powf(10000.f, -(float)i * (1.f / 32.f));
    float s, c;
    sincosf(ang, &s, &c);
    const u16* row = qkv + (size_t)t * 1536;
    const float QS = 0.125f * 1.4426950408889634f;  // attn scale * log2(e)
    const float cq = c * QS, sq = s * QS;
#pragma unroll
    for (int it = 0; it < 2; ++it) {
      int h = (tid >> 5) + it * 8;
      float x1 = bf2f(row[h * 64 + i]);
      float x2 = bf2f(row[h * 64 + 32 + i]);
      size_t o = ((size_t)h * T_SEQ + t) * 64 + i;
      Q[o] = f2bf(x1 * cq - x2 * sq);
      Q[o + 32] = f2bf(x2 * cq + x1 * sq);
    }
    if (tid < 128) {
      int h = tid >> 5;
      float x1 = bf2f(row[1024 + h * 64 + i]);
      float x2 = bf2f(row[1024 + h * 64 + 32 + i]);
      size_t o = ((size_t)h * T_SEQ + t) * 64 + i;
      Ko[o] = f2bf(x1 * c - x2 * s);
      Ko[o + 32] = f2bf(x2 * c + x1 * s);
    }
  } else {
    const int t = b - 4096;
    const int t0 = (t & 63) * 64, h = t >> 6;
    const int r = tid >> 2, q4 = (tid & 3) * 16;
    const u16* src = qkv + (size_t)(t0 + r) * 1536 + 1280 + h * 64 + q4;
    union { u16 s[16]; uint4 q[2]; } buf;
    buf.q[0] = *(const uint4*)(src);
    buf.q[1] = *(const uint4*)(src + 8);
#pragma unroll
    for (int j = 0; j < 16; ++j) tile[r][q4 + j] = buf.s[j];
    __syncthreads();
#pragma unroll
    for (int j = 0; j < 16; ++j) buf.s[j] = tile[q4 + j][r];
    u16* dst = Vt + ((size_t)h * 64 + r) * T_SEQ + t0 + q4;
    *(uint4*)(dst) = buf.q[0];
    *(uint4*)(dst + 8) = buf.q[1];
  }
}

// ---------------- bf16 GEMM: C[M][N] = A[M][K] @ Bt[N][K]^T ----------------
// R3: double-buffered LDS + prefetch-before-compute + ONE barrier per K-step.
// Used for the QKV projection (AM=2). W1 moved to gemm_ffn1 (256^2 tile).
template <int AM, int ACT, typename OutT>
__global__ void __launch_bounds__(256) gemm_bt(const u16* __restrict__ A,
                                               const u16* __restrict__ Bt,
                                               OutT* __restrict__ C,
                                               int M, int N, int K) {
  __shared__ u16 sA[2][AM * 32][64];
  __shared__ u16 sB[2][128][64];
  const int tid = threadIdx.x;
  const int w = tid >> 6, lane = tid & 63;
  const int g = lane >> 4, l15 = lane & 15;
  const int r8 = lane >> 3, c8 = lane & 7;
  const int bm = blockIdx.y * (AM * 32), bn = blockIdx.x * 128;

  f32x4 acc[AM][4];
#pragma unroll
  for (int i = 0; i < AM; ++i)
#pragma unroll
    for (int j = 0; j < 4; ++j) acc[i][j] = (f32x4){0.f, 0.f, 0.f, 0.f};

  const u16* Ag = A + (size_t)(bm + w * (AM * 8) + r8) * K + (c8 ^ r8) * 8;
  const u16* Bg = Bt + (size_t)(bn + w * 32 + r8) * K + (c8 ^ r8) * 8;
  const int mrow = (w >> 1) * (AM * 16), ncol = (w & 1) * 64;
  const int swz = l15 & 7;

#define GSTAGE(K0, BUF)                                                        \
  {                                                                            \
    _Pragma("unroll") for (int t = 0; t < AM; ++t)                             \
      async16(&sA[BUF][w * (AM * 8) + t * 8][0], Ag + (size_t)(t * 8) * K + (K0)); \
    _Pragma("unroll") for (int t = 0; t < 4; ++t)                              \
      async16(&sB[BUF][w * 32 + t * 8][0], Bg + (size_t)(t * 8) * K + (K0));   \
  }

  GSTAGE(0, 0);
  int cur = 0;
  for (int k0 = 0; k0 < K; k0 += 64) {
    __syncthreads();                       // drains prefetch of cur; protects cur^1 reuse
    if (k0 + 64 < K) GSTAGE(k0 + 64, cur ^ 1);
#pragma unroll
    for (int kk = 0; kk < 2; ++kk) {
      const int cb = ((kk * 4 + g) ^ swz) * 8;
      bf16x8 a[AM], b[4];
#pragma unroll
      for (int i = 0; i < AM; ++i) a[i] = *(const bf16x8*)&sA[cur][mrow + i * 16 + l15][cb];
#pragma unroll
      for (int i = 0; i < 4; ++i) b[i] = *(const bf16x8*)&sB[cur][ncol + i * 16 + l15][cb];
#pragma unroll
      for (int mi = 0; mi < AM; ++mi)
#pragma unroll
        for (int ni = 0; ni < 4; ++ni)
          acc[mi][ni] = __builtin_amdgcn_mfma_f32_16x16x32_bf16(a[mi], b[ni], acc[mi][ni], 0, 0, 0);
    }
    cur ^= 1;
  }
#undef GSTAGE
#pragma unroll
  for (int mi = 0; mi < AM; ++mi)
#pragma unroll
    for (int ni = 0; ni < 4; ++ni)
#pragma unroll
      for (int r = 0; r < 4; ++r) {
        int row = bm + mrow + mi * 16 + g * 4 + r;
        int col = bn + ncol + ni * 16 + l15;
        float v = acc[mi][ni][r];
        if (ACT == 1) v = v / (1.f + __expf(-v));  // SiLU
        storeC(C, (size_t)row * N + col, v);
      }
}

// ---------------- W1 GEMM: 256^2 tile, 512 threads, 8 waves (2M x 4N) ----------
// H[4096][4096] = SiLU(AO[4096][1024] @ W1T[4096][1024]^T), all bf16.
// R5 theory: 128^2 gemm_bt is register-locked at 2 waves/SIMD (acc AGPRs count
// against the unified file), so more blocks/CU is impossible; the remaining
// lever is tile size: 256^2 doubles FLOP per staged byte and raises FLOP per
// ds_read 2.2x (guide m248: 256^2-2ph = 655 TF @K=1024 vs our ~500). Same
// verified 2-barrier dbuf sync structure, same staging/swizzle formulas.
// LDS 128KB -> 1 block/CU (grid 256 = exactly 1/CU). acc[8][4]=128 regs.
__global__ void __launch_bounds__(512, 2) gemm_ffn1(const u16* __restrict__ A,
                                                    const u16* __restrict__ Bt,
                                                    u16* __restrict__ C) {
  const int N = 4096, K = 1024;
  __shared__ u16 sA[2][256][64];
  __shared__ u16 sB[2][256][64];
  const int tid = threadIdx.x;
  const int w = tid >> 6, lane = tid & 63;
  const int g = lane >> 4, l15 = lane & 15;
  const int r8 = lane >> 3, c8 = lane & 7;
  const int wm = w >> 2, wn = w & 3;          // 2 x 4 wave grid
  const int bm = blockIdx.y * 256, bn = blockIdx.x * 256;

  f32x4 acc[8][4];
#pragma unroll
  for (int i = 0; i < 8; ++i)
#pragma unroll
    for (int j = 0; j < 4; ++j) acc[i][j] = (f32x4){0.f, 0.f, 0.f, 0.f};

  // each wave stages 32 rows of A and 32 rows of B (8 waves cover 256)
  const u16* Ag = A + (size_t)(bm + w * 32 + r8) * K + (c8 ^ r8) * 8;
  const u16* Bg = Bt + (size_t)(bn + w * 32 + r8) * K + (c8 ^ r8) * 8;
  const int mrow = wm * 128, ncol = wn * 64;  // per-wave 128x64 output
  const int swz = l15 & 7;

#define FSTAGE(K0, BUF)                                                   \
  {                                                                       \
    _Pragma("unroll") for (int t = 0; t < 4; ++t) {                       \
      async16(&sA[BUF][w * 32 + t * 8][0], Ag + (size_t)(t * 8) * K + (K0)); \
      async16(&sB[BUF][w * 32 + t * 8][0], Bg + (size_t)(t * 8) * K + (K0)); \
    }                                                                     \
  }

  FSTAGE(0, 0);
  int cur = 0;
  for (int k0 = 0; k0 < K; k0 += 64) {
    __syncthreads();
    if (k0 + 64 < K) FSTAGE(k0 + 64, cur ^ 1);
#pragma unroll
    for (int kk = 0; kk < 2; ++kk) {
      const int cb = ((kk * 4 + g) ^ swz) * 8;
      bf16x8 a[8], b[4];
#pragma unroll
      for (int i = 0; i < 8; ++i) a[i] = *(const bf16x8*)&sA[cur][mrow + i * 16 + l15][cb];
#pragma unroll
      for (int i = 0; i < 4; ++i) b[i] = *(const bf16x8*)&sB[cur][ncol + i * 16 + l15][cb];
#pragma unroll
      for (int mi = 0; mi < 8; ++mi)
#pragma unroll
        for (int ni = 0; ni < 4; ++ni)
          acc[mi][ni] = __builtin_amdgcn_mfma_f32_16x16x32_bf16(a[mi], b[ni], acc[mi][ni], 0, 0, 0);
    }
    cur ^= 1;
  }
#undef FSTAGE
#pragma unroll
  for (int mi = 0; mi < 8; ++mi)
#pragma unroll
    for (int ni = 0; ni < 4; ++ni)
#pragma unroll
      for (int r = 0; r < 4; ++r) {
        int row = bm + mrow + mi * 16 + g * 4 + r;
        int col = bn + ncol + ni * 16 + l15;
        float v = acc[mi][ni][r];
        v = v / (1.f + __expf(-v));  // SiLU
        C[(size_t)row * N + col] = f2bf(v);
      }
}

// ---------------- W2 GEMM, AM=4 + split-K x2 ----------------
// out[4096][1024] (fp32) = H[4096][4096] @ W2T[1024][4096]^T.
// z=0 covers k<2048 -> fp32 partial straight into out; z=1 covers k>=2048 ->
// bf16 partial into P1 (aliases dead W1T). w2_combine: out += bf16(P1).
// R3: same double-buffer + prefetch-before-compute transformation as gemm_bt.
__global__ void __launch_bounds__(256, 2) gemm_w2(const u16* __restrict__ A,
                                                  const u16* __restrict__ Bt,
                                                  float* __restrict__ C0,
                                                  u16* __restrict__ C1) {
  __shared__ u16 sA[2][128][64];
  __shared__ u16 sB[2][128][64];
  const int K = 4096, N = 1024;
  const int z = blockIdx.z, koff = z * 2048;
  const int tid = threadIdx.x;
  const int w = tid >> 6, lane = tid & 63;
  const int g = lane >> 4, l15 = lane & 15;
  const int r8 = lane >> 3, c8 = lane & 7;
  const int bm = blockIdx.y * 128, bn = blockIdx.x * 128;

  f32x4 acc[4][4];
#pragma unroll
  for (int i = 0; i < 4; ++i)
#pragma unroll
    for (int j = 0; j < 4; ++j) acc[i][j] = (f32x4){0.f, 0.f, 0.f, 0.f};

  const u16* Ag = A + (size_t)(bm + w * 32 + r8) * K + koff + (c8 ^ r8) * 8;
  const u16* Bg = Bt + (size_t)(bn + w * 32 + r8) * K + koff + (c8 ^ r8) * 8;
  const int mrow = (w >> 1) * 64, ncol = (w & 1) * 64;
  const int swz = l15 & 7;

#define GSTAGE(K0, BUF)                                                   \
  {                                                                       \
    _Pragma("unroll") for (int t = 0; t < 4; ++t) {                       \
      async16(&sA[BUF][w * 32 + t * 8][0], Ag + (size_t)(t * 8) * K + (K0)); \
      async16(&sB[BUF][w * 32 + t * 8][0], Bg + (size_t)(t * 8) * K + (K0)); \
    }                                                                     \
  }

  GSTAGE(0, 0);
  int cur = 0;
  for (int k0 = 0; k0 < 2048; k0 += 64) {
    __syncthreads();
    if (k0 + 64 < 2048) GSTAGE(k0 + 64, cur ^ 1);
#pragma unroll
    for (int kk = 0; kk < 2; ++kk) {
      const int cb = ((kk * 4 + g) ^ swz) * 8;
      bf16x8 a[4], b[4];
#pragma unroll
      for (int i = 0; i < 4; ++i) {
        a[i] = *(const bf16x8*)&sA[cur][mrow + i * 16 + l15][cb];
        b[i] = *(const bf16x8*)&sB[cur][ncol + i * 16 + l15][cb];
      }
#pragma unroll
      for (int mi = 0; mi < 4; ++mi)
#pragma unroll
        for (int ni = 0; ni < 4; ++ni)
          acc[mi][ni] = __builtin_amdgcn_mfma_f32_16x16x32_bf16(a[mi], b[ni], acc[mi][ni], 0, 0, 0);
    }
    cur ^= 1;
  }
#undef GSTAGE
#pragma unroll
  for (int mi = 0; mi < 4; ++mi)
#pragma unroll
    for (int ni = 0; ni < 4; ++ni)
#pragma unroll
      for (int r = 0; r < 4; ++r) {
        size_t idx = (size_t)(bm + mrow + mi * 16 + g * 4 + r) * N + bn + ncol + ni * 16 + l15;
        if (z == 0) C0[idx] = acc[mi][ni][r];
        else        C1[idx] = f2bf(acc[mi][ni][r]);
      }
}

__global__ void __launch_bounds__(256) w2_combine(float* __restrict__ out,
                                                  const u16* __restrict__ P1) {
  int idx = (blockIdx.x * 256 + threadIdx.x) * 4;
  float4 v = *(const float4*)(out + idx);
  union { uint2 q; u16 s[4]; } p;
  p.q = *(const uint2*)(P1 + idx);
  v.x += bf2f(p.s[0]); v.y += bf2f(p.s[1]);
  v.z += bf2f(p.s[2]); v.w += bf2f(p.s[3]);
  *(float4*)(out + idx) = v;
}

// ---------------- Flash attention (causal, GQA 16q/4kv, D=64) ----------------
// 128-row q-tile pairs (t0=pr, t1=31-pr) x kv-parity split: 512 equal blocks.
// R4: 1-tile software pipeline (T15). Per iter: QK(i) [matrix] -> PV(i-1)
// [matrix, independent, reads sP from last iter] -> exp/pack(i) [VALU, waits
// only on QK(i), overlaps PV's MFMAs] -> sP write. V gets a 3rd buffer so
// STAGE(i+1) never overwrites V(i-1) mid-PV. sP stays full-size, halves stay
// parallel (R1 lesson). LDS 74.8KB -> still 2 blocks/CU.
__global__ void __launch_bounds__(256, 2) attn(const u16* __restrict__ Q,
                                               const u16* __restrict__ K,
                                               const u16* __restrict__ Vt,
                                               u16* __restrict__ O0,
                                               u16* __restrict__ O1,
                                               float* __restrict__ L0,
                                               float* __restrict__ L1) {
  __shared__ u16 sK[2][64][64];
  __shared__ u16 sV[3][64][64];     // sV[vb][d][kv], triple-buffered
  __shared__ u16 sP[4][64][68];     // [wave][half*32+mi*16+q16][kv] pad+4
  const int pr = blockIdx.x >> 1;
  const int split = blockIdx.x & 1;
  const int h = blockIdx.y;
  const int kvh = h >> 2;
  const int tid = threadIdx.x;
  const int w = tid >> 6, lane = tid & 63;
  const int g = lane >> 4, l15 = lane & 15;
  const int r8 = lane >> 3, c8 = lane & 7;
  const int swz = l15 & 7;
  const int t0 = pr, t1 = 31 - pr;
  const int off = split * 64;

  u16* Op = split ? O1 : O0;
  float* Lp = split ? L1 : L0;

  bf16x8 qf[2][2][2];
  {
    const u16* Qh = Q + (size_t)h * T_SEQ * 64;
#pragma unroll
    for (int half = 0; half < 2; ++half)
#pragma unroll
      for (int mi = 0; mi < 2; ++mi) {
        const int q = (half ? t1 : t0) * 128 + w * 32 + mi * 16 + l15;
#pragma unroll
        for (int kk = 0; kk < 2; ++kk)
          qf[half][mi][kk] = *(const bf16x8*)(Qh + (size_t)q * 64 + (kk * 4 + g) * 8);
      }
  }

  f32x4 oacc[2][2][4];
  f32x4 lacc[2][2];
#pragma unroll
  for (int half = 0; half < 2; ++half)
#pragma unroll
    for (int mi = 0; mi < 2; ++mi) {
      lacc[half][mi] = (f32x4){0.f, 0.f, 0.f, 0.f};
#pragma unroll
      for (int nd = 0; nd < 4; ++nd) oacc[half][mi][nd] = (f32x4){0.f, 0.f, 0.f, 0.f};
    }

  bf16x8 ONES;
  {
    union { u16 s[8]; bf16x8 v; } o;
#pragma unroll
    for (int i = 0; i < 8; ++i) o.s[i] = 0x3F80;  // bf16 1.0
    ONES = o.v;
  }

  const u16* Kg = K + ((size_t)kvh * T_SEQ + w * 16 + r8) * 64 + (c8 ^ r8) * 8;
  const u16* Vg = Vt + ((size_t)kvh * 64 + w * 16 + r8) * T_SEQ + (c8 ^ r8) * 8;

  f32x4 s1[2][4], s0[2][4];        // QK scores of current tile (transient)
  uint2 pk1[2][4], pk0[2][4];      // packed P of current tile (written to sP at iter end)

#define STAGE2(J, KB, VB)                                               \
  {                                                                     \
    const int kv0_ = (J) * 64;                                          \
    async16(&sK[KB][w * 16 + 0][0], Kg + (size_t)kv0_ * 64);            \
    async16(&sK[KB][w * 16 + 8][0], Kg + (size_t)(kv0_ + 8) * 64);      \
    async16(&sV[VB][w * 16 + 0][0], Vg + kv0_);                         \
    async16(&sV[VB][w * 16 + 8][0], Vg + (size_t)8 * T_SEQ + kv0_);     \
  }

#define QKMM(B, ACT0)                                                             \
  {                                                                               \
    _Pragma("unroll") for (int mi = 0; mi < 2; ++mi)                              \
    _Pragma("unroll") for (int kt = 0; kt < 4; ++kt) {                            \
      s1[mi][kt] = (f32x4){0.f, 0.f, 0.f, 0.f};                                   \
      if (ACT0) s0[mi][kt] = (f32x4){0.f, 0.f, 0.f, 0.f};                         \
    }                                                                             \
    __builtin_amdgcn_s_setprio(1);                                                \
    _Pragma("unroll") for (int kt = 0; kt < 4; ++kt)                              \
    _Pragma("unroll") for (int kk = 0; kk < 2; ++kk) {                            \
      bf16x8 kf = *(const bf16x8*)&sK[B][kt * 16 + l15][((kk * 4 + g) ^ swz) * 8]; \
      _Pragma("unroll") for (int mi = 0; mi < 2; ++mi) {                          \
        s1[mi][kt] = __builtin_amdgcn_mfma_f32_16x16x32_bf16(kf, qf[1][mi][kk], s1[mi][kt], 0, 0, 0); \
        if (ACT0)                                                                 \
          s0[mi][kt] = __builtin_amdgcn_mfma_f32_16x16x32_bf16(kf, qf[0][mi][kk], s0[mi][kt], 0, 0, 0); \
      }                                                                           \
    }                                                                             \
    __builtin_amdgcn_s_setprio(0);                                                \
  }

// PV + l-acc of the PREVIOUS tile: reads sP (written last iter) + sV[VB].
#define PVL(PACT0, VB)                                                            \
  {                                                                               \
    __builtin_amdgcn_s_setprio(1);                                                \
    _Pragma("unroll") for (int kk = 0; kk < 2; ++kk) {                            \
      bf16x8 pf1[2], pf0[2];                                                      \
      _Pragma("unroll") for (int mi = 0; mi < 2; ++mi) {                          \
        pf1[mi] = *(const bf16x8*)&sP[w][32 + mi * 16 + l15][kk * 32 + g * 8];    \
        if (PACT0) pf0[mi] = *(const bf16x8*)&sP[w][mi * 16 + l15][kk * 32 + g * 8]; \
      }                                                                           \
      _Pragma("unroll") for (int mi = 0; mi < 2; ++mi) {                          \
        lacc[1][mi] = __builtin_amdgcn_mfma_f32_16x16x32_bf16(pf1[mi], ONES, lacc[1][mi], 0, 0, 0); \
        if (PACT0)                                                                \
          lacc[0][mi] = __builtin_amdgcn_mfma_f32_16x16x32_bf16(pf0[mi], ONES, lacc[0][mi], 0, 0, 0); \
      }                                                                           \
      _Pragma("unroll") for (int nd = 0; nd < 4; ++nd) {                          \
        bf16x8 vf = *(const bf16x8*)&sV[VB][nd * 16 + l15][((kk * 4 + g) ^ swz) * 8]; \
        _Pragma("unroll") for (int mi = 0; mi < 2; ++mi) {                        \
          oacc[1][mi][nd] = __builtin_amdgcn_mfma_f32_16x16x32_bf16(pf1[mi], vf, oacc[1][mi][nd], 0, 0, 0); \
          if (PACT0)                                                              \
            oacc[0][mi][nd] = __builtin_amdgcn_mfma_f32_16x16x32_bf16(pf0[mi], vf, oacc[0][mi][nd], 0, 0, 0); \
        }                                                                         \
      }                                                                           \
    }                                                                             \
    __builtin_amdgcn_s_setprio(0);                                                \
  }

// exp + causal-mask + pack of current tile's scores into pk regs.
#define EXPPK(ACT0, M0, M1)                                                       \
  {                                                                               \
    _Pragma("unroll") for (int mi = 0; mi < 2; ++mi) {                            \
      const int thr_ = w * 32 + mi * 16 + l15 - off;                              \
      _Pragma("unroll") for (int kt = 0; kt < 4; ++kt) {                          \
        float p_[4];                                                              \
        _Pragma("unroll") for (int r = 0; r < 4; ++r) {                           \
          float p = fexp2(s1[mi][kt][r]);                                         \
          if (M1 && (kt * 16 + g * 4 + r > thr_)) p = 0.f;                        \
          p_[r] = p;                                                              \
        }                                                                         \
        pk1[mi][kt].x = pack_bf16(p_[0], p_[1]);                                  \
        pk1[mi][kt].y = pack_bf16(p_[2], p_[3]);                                  \
        if (ACT0) {                                                               \
          float q_[4];                                                            \
          _Pragma("unroll") for (int r = 0; r < 4; ++r) {                         \
            float p = fexp2(s0[mi][kt][r]);                                       \
            if (M0 && (kt * 16 + g * 4 + r > thr_)) p = 0.f;                      \
            q_[r] = p;                                                            \
          }                                                                       \
          pk0[mi][kt].x = pack_bf16(q_[0], q_[1]);                                \
          pk0[mi][kt].y = pack_bf16(q_[2], q_[3]);                                \
        }                                                                         \
      }                                                                           \
    }                                                                             \
  }

#define SPW(ACT0)                                                                 \
  {                                                                               \
    _Pragma("unroll") for (int mi = 0; mi < 2; ++mi)                              \
    _Pragma("unroll") for (int kt = 0; kt < 4; ++kt) {                            \
      *(uint2*)&sP[w][32 + mi * 16 + l15][kt * 16 + g * 4] = pk1[mi][kt];         \
      if (ACT0) *(uint2*)&sP[w][mi * 16 + l15][kt * 16 + g * 4] = pk0[mi][kt];    \
    }                                                                             \
  }

  // Tile sequence: i = 0..t1, kv-block jj = split + 2i. Tile i is:
  //   i < t0 : dual, no mask;  i == t0 : dual, mask half0;
  //   t0 < i < t1 : single (half1);  i == t1 : single, masked.
  // Pipeline invariant entering iter i: vp = V(T_{i-1}), vc = V(T_i), vn free;
  // sP holds P(T_{i-1}); sK[b] = K(T_i) (staged last iter).
  // --- prologue: tile 0 ---
  STAGE2(split, 0, 0);
  __syncthreads();
  STAGE2(split + 2, 1, 1);             // tile 1 always exists (t1 >= 16)
  QKMM(0, true);
  if (t0 == 0) { EXPPK(true, true, false); }
  else         { EXPPK(true, false, false); }
  SPW(true);
  int b = 1;
  int vp = 0, vc = 1, vn = 2;
  int i = 1;
  // --- P1: dual, no mask (prev dual) ---
  for (; i < t0; ++i) {
    __syncthreads();
    STAGE2(split + 2 * (i + 1), b ^ 1, vn);
    QKMM(b, true);
    PVL(true, vp);
    EXPPK(true, false, false);
    __builtin_amdgcn_wave_barrier();
    SPW(true);
    b ^= 1; int tmp = vp; vp = vc; vc = vn; vn = tmp;
  }
  // --- P2: i == t0 (if t0 >= 1): dual, mask half0 (prev dual) ---
  if (t0 >= 1) {
    __syncthreads();
    STAGE2(split + 2 * (i + 1), b ^ 1, vn);   // i+1 = t0+1 <= t1
    QKMM(b, true);
    PVL(true, vp);
    EXPPK(true, true, false);
    __builtin_amdgcn_wave_barrier();
    SPW(true);
    b ^= 1; int tmp = vp; vp = vc; vc = vn; vn = tmp;
    ++i;
  }
  if (i < t1) {
    // --- P3a: first single (prev dual) ---
    __syncthreads();
    STAGE2(split + 2 * (i + 1), b ^ 1, vn);
    QKMM(b, false);
    PVL(true, vp);
    EXPPK(false, false, false);
    __builtin_amdgcn_wave_barrier();
    SPW(false);
    b ^= 1; { int tmp = vp; vp = vc; vc = vn; vn = tmp; }
    ++i;
    // --- P3: singles (prev single) ---
    for (; i < t1; ++i) {
      __syncthreads();
      STAGE2(split + 2 * (i + 1), b ^ 1, vn);
      QKMM(b, false);
      PVL(false, vp);
      EXPPK(false, false, false);
      __builtin_amdgcn_wave_barrier();
      SPW(false);
      b ^= 1; int tmp = vp; vp = vc; vc = vn; vn = tmp;
    }
    // --- P4: i == t1: single, masked (prev single) ---
    __syncthreads();
    QKMM(b, false);
    PVL(false, vp);
    EXPPK(false, false, true);
    __builtin_amdgcn_wave_barrier();
    SPW(false);
    // --- drain: PV of last tile (single) ---
    __builtin_amdgcn_wave_barrier();
    PVL(false, vc);
  } else {
    // t1 == t0 + 1 (pr == 15): P4 directly, prev = dual-masked tile
    __syncthreads();
    QKMM(b, false);
    PVL(true, vp);
    EXPPK(false, false, true);
    __builtin_amdgcn_wave_barrier();
    SPW(false);
    __builtin_amdgcn_wave_barrier();
    PVL(false, vc);
  }
#undef STAGE2
#undef QKMM
#undef PVL
#undef EXPPK
#undef SPW

  // epilogue: write UNNORMALIZED partial O (bf16) + partial l (f32)
#pragma unroll
  for (int half = 0; half < 2; ++half) {
    const int tb = (half ? t1 : t0) * 128;
#pragma unroll
    for (int mi = 0; mi < 2; ++mi)
#pragma unroll
      for (int r = 0; r < 4; ++r) {
        const int trow = tb + w * 32 + mi * 16 + g * 4 + r;
#pragma unroll
        for (int nd = 0; nd < 4; ++nd)
          Op[(size_t)trow * DMODEL + h * 64 + nd * 16 + l15] = f2bf(oacc[half][mi][nd][r]);
        if (l15 == 0) Lp[h * T_SEQ + trow] = lacc[half][mi][r];
      }
  }
}

// ---------------- combine partials: AO = (O0+O1)/(l0+l1) ----------------
__global__ void __launch_bounds__(256) attn_combine(const u16* __restrict__ O0,
                                                    const u16* __restrict__ O1,
                                                    const float* __restrict__ L0,
                                                    const float* __restrict__ L1,
                                                    u16* __restrict__ AO) {
  const int t = blockIdx.x, tid = threadIdx.x;
  const int h = tid >> 4, d4 = (tid & 15) * 4;
  const float inv = 1.f / (L0[h * T_SEQ + t] + L1[h * T_SEQ + t]);
  const size_t idx = (size_t)t * DMODEL + h * 64 + d4;
  union { uint2 q; u16 s[4]; } a, b, o;
  a.q = *(const uint2*)(O0 + idx);
  b.q = *(const uint2*)(O1 + idx);
#pragma unroll
  for (int i = 0; i < 4; ++i) o.s[i] = f2bf((bf2f(a.s[i]) + bf2f(b.s[i])) * inv);
  *(uint2*)(AO + idx) = o.q;
}

// ---------------------------------------------------------------------------
extern "C" void kernel_launch(void* const* d_in, const int* in_sizes, int n_in,
                              void* d_out, int out_size, void* d_ws, size_t ws_size,
                              hipStream_t stream) {
  const float* query = (const float*)d_in[0];
  const float* Wq = (const float*)d_in[1];
  const float* Wk = (const float*)d_in[2];
  const float* Wv = (const float*)d_in[3];
  const float* W1 = (const float*)d_in[4];
  const float* W2 = (const float*)d_in[5];
  float* out = (float*)d_out;

  char* ws = (char*)d_ws;
  size_t off = 0;
  auto alloc = [&](size_t bytes) { char* p = ws + off; off += (bytes + 255) & ~(size_t)255; return p; };
  // Region A (32 MB) -- all dead after attention; H aliases it.
  u16* Xb   = (u16*)alloc((size_t)4096 * 1024 * 2);
  u16* QKVb = (u16*)alloc((size_t)4096 * 1536 * 2);
  u16* Qb   = (u16*)alloc((size_t)16 * 4096 * 64 * 2);
  u16* Kb   = (u16*)alloc((size_t)4 * 4096 * 64 * 2);
  u16* Vtb  = (u16*)alloc((size_t)4 * 4096 * 64 * 2);
  u16* H    = (u16*)ws;  // [4096][4096] bf16 = 32 MB, aliases region A
  // Attention partials alias Xb / QKVb (dead by the time attn runs):
  u16*   O0p = Xb;                               // 8 MB
  u16*   O1p = QKVb;                             // 8 MB
  float* L0p = (float*)(QKVb + (size_t)4096 * 1024);  // 256 KB
  float* L1p = L0p + 16 * T_SEQ;                      // 256 KB
  // Region B
  u16* WqkvT = (u16*)alloc((size_t)1536 * 1024 * 2);
  u16* W1T   = (u16*)alloc((size_t)4096 * 1024 * 2);
  u16* W2T   = (u16*)alloc((size_t)1024 * 4096 * 2);
  u16* AO    = (u16*)alloc((size_t)4096 * 1024 * 2);
  u16* P1    = W1T;  // W2 split-K bf16 partial, aliases dead W1T (8 MB)
  (void)ws_size; (void)in_sizes; (void)n_in; (void)out_size;

  prep<<<6528, 256, 0, stream>>>(query, Wq, Wk, Wv, W1, W2, Xb, WqkvT, W1T, W2T);
  gemm_bt<2, 0, u16><<<dim3(12, 64), 256, 0, stream>>>(Xb, WqkvT, QKVb, 4096, 1536, 1024);
  rope_vt<<<4352, 256, 0, stream>>>(QKVb, Qb, Kb, Vtb);
  attn<<<dim3(32, 16), 256, 0, stream>>>(Qb, Kb, Vtb, O0p, O1p, L0p, L1p);
  attn_combine<<<4096, 256, 0, stream>>>(O0p, O1p, L0p, L1p, AO);
  gemm_ffn1<<<dim3(16, 16), 512, 0, stream>>>(AO, W1T, H);
  gemm_w2<<<dim3(8, 32, 2), 256, 0, stream>>>(H, W2T, out, P1);
  w2_combine<<<4096, 256, 0, stream>>>(out, P1);
}